// Round 2
// baseline (496.774 us; speedup 1.0000x reference)
//
#include <hip/hip_runtime.h>
#include <hip/hip_bf16.h>

typedef __attribute__((ext_vector_type(8))) short bf16x8;
typedef __attribute__((ext_vector_type(4))) float f32x4;

#define B_ 32
#define E_ 8
#define O_ 192
#define I_ 192
#define H_ 56
#define W_ 56
#define HW_ 3136
#define IK_ (I_ * 9)
#define WSZ_ (O_ * IK_)

// Workspace layout (bf16 elems unless noted):
//   whi/wlo: [b][9][24][192][8]   (10,616,832 each)
//   xhi/xlo: [b][3136][192]       (19,267,584 each)
//   bmix:    [b][192] float
#define WT_E ((size_t)B_ * 9 * 24 * 192 * 8)
#define XT_E ((size_t)B_ * HW_ * 192)

static __device__ __forceinline__ unsigned short f2bf(float v) {
    __hip_bfloat16 h = __float2bfloat16(v);
    return *reinterpret_cast<unsigned short*>(&h);
}
static __device__ __forceinline__ float bf2f(unsigned short u) {
    __hip_bfloat16 h = *reinterpret_cast<__hip_bfloat16*>(&u);
    return __bfloat162float(h);
}

// ---------------------------------------------------------------------------
// Mix experts -> per-batch weights, split fp32 into bf16 hi/lo, transpose to
// [b][s][i/8][o][i%8]; also produce mixed bias bmix[b][o].
// ---------------------------------------------------------------------------
__global__ __launch_bounds__(256) void mix_split_w(
    const float* __restrict__ r, const float* __restrict__ Wt,
    const float* __restrict__ bias, unsigned short* __restrict__ whi,
    unsigned short* __restrict__ wlo, float* __restrict__ bmix) {
    __shared__ float rs[B_ * E_];
    int t = threadIdx.x;
    rs[t] = r[t];  // 256 == 32*8
    __syncthreads();
    int gid = blockIdx.x * 256 + t;

    if (gid < B_ * O_) {
        int b = gid / O_, o = gid - b * O_;
        float acc = 0.f;
#pragma unroll
        for (int e = 0; e < E_; ++e)
            acc = fmaf(rs[b * E_ + e], bias[e * O_ + o], acc);
        bmix[gid] = acc;
    }
    if (gid >= O_ * I_) return;
    int o = gid / I_, i = gid - o * I_;

    float we[E_][9];
#pragma unroll
    for (int e = 0; e < E_; ++e)
#pragma unroll
        for (int s = 0; s < 9; ++s)
            we[e][s] = Wt[(size_t)e * WSZ_ + (size_t)gid * 9 + s];

    for (int b = 0; b < B_; ++b) {
#pragma unroll
        for (int s = 0; s < 9; ++s) {
            float v = 0.f;
#pragma unroll
            for (int e = 0; e < E_; ++e) v = fmaf(rs[b * E_ + e], we[e][s], v);
            unsigned short h = f2bf(v);
            unsigned short l = f2bf(v - bf2f(h));
            size_t oidx =
                ((((size_t)(b * 9 + s)) * 24 + (i >> 3)) * 192 + o) * 8 +
                (i & 7);
            whi[oidx] = h;
            wlo[oidx] = l;
        }
    }
}

// ---------------------------------------------------------------------------
// Split x into bf16 hi/lo and transpose [b][i][hw] -> [b][hw][i].
// ---------------------------------------------------------------------------
__global__ __launch_bounds__(256) void split_x(
    const float* __restrict__ x, unsigned short* __restrict__ xhi,
    unsigned short* __restrict__ xlo) {
    __shared__ float tile[64][65];
    int t = threadIdx.x;
    int tx = t & 63, ty = t >> 6;
    int b = blockIdx.z, i0 = blockIdx.y * 64, hw0 = blockIdx.x * 64;
    const float* xb = x + ((size_t)b * I_ + i0) * HW_ + hw0;
#pragma unroll
    for (int k = 0; k < 16; ++k) {
        int il = ty * 16 + k;
        tile[il][tx] = xb[(size_t)il * HW_ + tx];
    }
    __syncthreads();
#pragma unroll
    for (int k = 0; k < 16; ++k) {
        int hwl = ty * 16 + k;
        float v = tile[tx][hwl];
        unsigned short h = f2bf(v);
        unsigned short l = f2bf(v - bf2f(h));
        size_t oidx = ((size_t)b * HW_ + hw0 + hwl) * I_ + i0 + tx;
        xhi[oidx] = h;
        xlo[oidx] = l;
    }
}

// ---------------------------------------------------------------------------
// MFMA conv. Block = 128 thr (2 waves). Block tile: 96 o x 112 p (2 h-rows).
// Wave tile: 48 o (M_rep=3) x 112 p (N_rep=7), 16x16x32 bf16 MFMA, split-3.
// LDS: x chunk [4 rows][58 cols][32 i] bf16, hi+lo = 29.7 KB, XOR-swizzled
// 16B chunks (slot = c ^ ((row>>1)&3)) for bank-floor ds_read/write_b128.
// ---------------------------------------------------------------------------
__global__ __launch_bounds__(128, 2) void conv_mfma(
    const unsigned short* __restrict__ xhi,
    const unsigned short* __restrict__ xlo,
    const unsigned short* __restrict__ whi,
    const unsigned short* __restrict__ wlo,
    const float* __restrict__ bmix, float* __restrict__ out) {
    __shared__ __align__(16) unsigned char xs[2 * 14848];

    const int t = threadIdx.x;
    const int lane = t & 63, wv = t >> 6;
    const int lc = lane & 15, g = lane >> 4;
    const int h0 = blockIdx.x * 2;
    const int ob = blockIdx.y * 96 + wv * 48;
    const int b = blockIdx.z;

    int rowbase[7];
#pragma unroll
    for (int f = 0; f < 7; ++f) {
        int ploc = f * 16 + lc;
        int hh = (ploc >= 56) ? 1 : 0;
        int wl = ploc - 56 * hh;
        rowbase[f] = hh * 58 + wl;
    }

    f32x4 acc[3][7];
#pragma unroll
    for (int mi = 0; mi < 3; ++mi)
#pragma unroll
        for (int f = 0; f < 7; ++f) acc[mi][f] = (f32x4){0.f, 0.f, 0.f, 0.f};

    for (int icb = 0; icb < 6; ++icb) {
        __syncthreads();
        // ---- stage x chunk (both waves): 232 rows x 4 chunks x 16B, hi+lo
#pragma unroll
        for (int it = 0; it < 8; ++it) {
            int idx = it * 128 + t;
            if (idx < 928) {
                int row = idx >> 2, c = idx & 3;
                int rr = row / 58, ww = row - rr * 58;
                int h = h0 - 1 + rr, w = ww - 1;
                bf16x8 vh = (bf16x8){0, 0, 0, 0, 0, 0, 0, 0};
                bf16x8 vl = (bf16x8){0, 0, 0, 0, 0, 0, 0, 0};
                if ((unsigned)h < (unsigned)H_ && (unsigned)w < (unsigned)W_) {
                    size_t goff =
                        ((size_t)(b * HW_ + h * W_ + w)) * 192 + icb * 32 +
                        c * 8;
                    vh = *(const bf16x8*)(xhi + goff);
                    vl = *(const bf16x8*)(xlo + goff);
                }
                int off = row * 64 + ((c ^ ((row >> 1) & 3)) << 4);
                *(bf16x8*)(xs + off) = vh;
                *(bf16x8*)(xs + 14848 + off) = vl;
            }
        }
        __syncthreads();

#pragma unroll
        for (int s = 0; s < 9; ++s) {
            const int dh = s / 3, dw = s - dh * 3;
            bf16x8 ah[3], al[3];
#pragma unroll
            for (int mi = 0; mi < 3; ++mi) {
                size_t aidx =
                    ((((size_t)(b * 9 + s)) * 24 + icb * 4 + g) * 192 +
                     (ob + mi * 16 + lc)) * 8;
                ah[mi] = *(const bf16x8*)(whi + aidx);
                al[mi] = *(const bf16x8*)(wlo + aidx);
            }
#pragma unroll
            for (int f = 0; f < 7; ++f) {
                int row = rowbase[f] + dh * 58 + dw;
                int off = row * 64 + (((g ^ (row >> 1)) & 3) << 4);
                bf16x8 bh = *(const bf16x8*)(xs + off);
                bf16x8 bl = *(const bf16x8*)(xs + 14848 + off);
#pragma unroll
                for (int mi = 0; mi < 3; ++mi) {
                    acc[mi][f] = __builtin_amdgcn_mfma_f32_16x16x32_bf16(
                        ah[mi], bh, acc[mi][f], 0, 0, 0);
                    acc[mi][f] = __builtin_amdgcn_mfma_f32_16x16x32_bf16(
                        ah[mi], bl, acc[mi][f], 0, 0, 0);
                    acc[mi][f] = __builtin_amdgcn_mfma_f32_16x16x32_bf16(
                        al[mi], bh, acc[mi][f], 0, 0, 0);
                }
            }
        }
    }

    // ---- epilogue: D layout col=lane&15 (p), row=(lane>>4)*4+j (o)
#pragma unroll
    for (int mi = 0; mi < 3; ++mi) {
#pragma unroll
        for (int j = 0; j < 4; ++j) {
            int o = ob + mi * 16 + g * 4 + j;
            float bs = bmix[b * O_ + o];
            float* op = out + ((size_t)(b * O_ + o)) * HW_;
#pragma unroll
            for (int f = 0; f < 7; ++f) {
                int ploc = f * 16 + lc;
                int hh = (ploc >= 56) ? 1 : 0;
                int wl = ploc - 56 * hh;
                op[(h0 + hh) * W_ + wl] = acc[mi][f][j] + bs;
            }
        }
    }
}

// ---------------------------------------------------------------------------
// fp32 fallback (on-the-fly mix), used only if ws_size is too small.
// ---------------------------------------------------------------------------
__global__ __launch_bounds__(256, 2) void condconv_fp32(
    const float* __restrict__ x, const float* __restrict__ wsrc,
    const float* __restrict__ r, const float* __restrict__ bias,
    float* __restrict__ out) {
    __shared__ float xsf[16][6][58];
    __shared__ float wsm[16 * 9][68];

    const int t = threadIdx.x;
    const int wg = t & 7;
    const int hg = (t >> 3) & 1;
    const int og = t >> 4;
    const int h0 = blockIdx.x * 4;
    const int o0 = blockIdx.y * 64;
    const int b = blockIdx.z;
    const float* xb = x + (size_t)b * I_ * H_ * W_;

    float rb[E_];
#pragma unroll
    for (int e = 0; e < E_; ++e) rb[e] = r[b * E_ + e];

    float acc[4][2][7];
#pragma unroll
    for (int oo = 0; oo < 4; ++oo)
#pragma unroll
        for (int hh = 0; hh < 2; ++hh)
#pragma unroll
            for (int ww = 0; ww < 7; ++ww) acc[oo][hh][ww] = 0.f;

    for (int ic = 0; ic < I_; ic += 16) {
        __syncthreads();
        for (int idx = t; idx < 16 * 6 * 58; idx += 256) {
            int ch = idx / (6 * 58);
            int rem = idx - ch * (6 * 58);
            int rr = rem / 58;
            int cc = rem - rr * 58;
            int hgl = h0 - 1 + rr;
            int wgl = cc - 1;
            float v = 0.f;
            if ((unsigned)hgl < H_ && (unsigned)wgl < W_)
                v = xb[(size_t)(ic + ch) * (H_ * W_) + hgl * W_ + wgl];
            ((float*)xsf)[idx] = v;
        }
        for (int idx = t; idx < 64 * 144; idx += 256) {
            int o = idx / 144;
            int ikl = idx - o * 144;
            float v = 0.f;
#pragma unroll
            for (int e = 0; e < E_; ++e)
                v = fmaf(rb[e],
                         wsrc[(size_t)e * WSZ_ + (size_t)(o0 + o) * IK_ +
                              ic * 9 + ikl],
                         v);
            wsm[ikl][o] = v;
        }
        __syncthreads();
        for (int i = 0; i < 16; ++i) {
#pragma unroll
            for (int kh = 0; kh < 3; ++kh) {
                float xr[2][9];
#pragma unroll
                for (int hh = 0; hh < 2; ++hh)
#pragma unroll
                    for (int c = 0; c < 9; ++c)
                        xr[hh][c] = xsf[i][hg * 2 + hh + kh][wg * 7 + c];
#pragma unroll
                for (int kw = 0; kw < 3; ++kw) {
                    float4 wv = *(const float4*)&wsm[i * 9 + kh * 3 + kw][og * 4];
                    float wreg[4] = {wv.x, wv.y, wv.z, wv.w};
#pragma unroll
                    for (int oo = 0; oo < 4; ++oo)
#pragma unroll
                        for (int hh = 0; hh < 2; ++hh)
#pragma unroll
                            for (int ww = 0; ww < 7; ++ww)
                                acc[oo][hh][ww] = fmaf(wreg[oo], xr[hh][kw + ww],
                                                       acc[oo][hh][ww]);
                }
            }
        }
    }
#pragma unroll
    for (int oo = 0; oo < 4; ++oo) {
        int o = o0 + og * 4 + oo;
        float bs = 0.f;
#pragma unroll
        for (int e = 0; e < E_; ++e) bs = fmaf(rb[e], bias[e * O_ + o], bs);
        float* ob = out + ((size_t)b * O_ + o) * (H_ * W_);
#pragma unroll
        for (int hh = 0; hh < 2; ++hh) {
            int h = h0 + hg * 2 + hh;
#pragma unroll
            for (int ww = 0; ww < 7; ++ww)
                ob[h * W_ + wg * 7 + ww] = acc[oo][hh][ww] + bs;
        }
    }
}

extern "C" void kernel_launch(void* const* d_in, const int* in_sizes, int n_in,
                              void* d_out, int out_size, void* d_ws,
                              size_t ws_size, hipStream_t stream) {
    const float* x = (const float*)d_in[0];
    const float* r = (const float*)d_in[1];
    const float* Wt = (const float*)d_in[2];
    const float* bias = (const float*)d_in[3];
    float* out = (float*)d_out;

    const size_t need = 2 * WT_E * 2 + 2 * XT_E * 2 + (size_t)B_ * O_ * 4;

    if (ws_size >= need) {
        unsigned char* p = (unsigned char*)d_ws;
        unsigned short* whi = (unsigned short*)p; p += WT_E * 2;
        unsigned short* wlo = (unsigned short*)p; p += WT_E * 2;
        unsigned short* xh = (unsigned short*)p; p += XT_E * 2;
        unsigned short* xl = (unsigned short*)p; p += XT_E * 2;
        float* bmix = (float*)p;

        mix_split_w<<<(O_ * I_) / 256, 256, 0, stream>>>(r, Wt, bias, whi, wlo,
                                                         bmix);
        split_x<<<dim3(HW_ / 64, I_ / 64, B_), 256, 0, stream>>>(x, xh, xl);
        conv_mfma<<<dim3(H_ / 2, 2, B_), 128, 0, stream>>>(xh, xl, whi, wlo,
                                                           bmix, out);
    } else {
        condconv_fp32<<<dim3(H_ / 4, O_ / 64, B_), 256, 0, stream>>>(x, Wt, r,
                                                                     bias, out);
    }
}